// Round 5
// baseline (4008.270 us; speedup 1.0000x reference)
//
#include <hip/hip_runtime.h>
#include <hip/hip_bf16.h>
#include <math.h>

// FactorizedVectorQuantizer MI355X (gfx950) — R5: swizzled LDS GEMM, 8x16 tile.
//
// rows 32768, feats 256 = 128 shape + 128 color; codebooks 8192x128, 512x128.
// Bit-exact numpy pipeline: D = fmaf(-2, dot, S + t); dot and S are single
// serial ascending-k fp32 FMA chains; argmin = lowest index on ties via
// packed u64 atomicMin key (mono(D)<<32 | code).
//
// gemm_argmin_k: 128 rows x 256 codes x K=128 (BK=32 x 4), 256 thr,
// 8x16 micro-tile (rows tr*4,+64; cols tcg*4,+64,+128,+192).
// LDS quad-XOR swizzle (slot = quad ^ k) -> conflict-free X writes/reads,
// 4-way residual only on W-transpose writes. 6 ds_read_b128 per 128 FMA.

#define NROWS   32768
#define NSHAPE  8192
#define NCOLOR  512
#define HALF    128

#define NSB     8192                // 256 rowblks x 32 colblks (shape)
#define NCB     512                 // 256 rowblks x 2 colblks (color)
#define NBLKS   (NSB + NCB)         // 8704, divisible by 8

// workspace byte offsets
#define OFF_TS    0u                // f32[8192]
#define OFF_TC    32768u            // f32[512]
#define OFF_CNT_S 34816u            // u32[8192]
#define OFF_CNT_C 67584u            // u32[512]
#define OFF_LOSS  69632u            // double
#define OFF_SS    69648u            // f32[32768]
#define OFF_SC    200720u           // f32[32768]
#define OFF_BS    331792u           // u64[32768] packed best (shape)
#define OFF_BC    593936u           // u64[32768] packed best (color)
#define OFF_END   856080u

__device__ __forceinline__ unsigned mono_f32(float d) {
    unsigned u = __float_as_uint(d);
    return (u & 0x80000000u) ? ~u : (u | 0x80000000u);
}

__global__ __launch_bounds__(256) void codes_sq_k(
    const float* __restrict__ Ws, const float* __restrict__ Wc,
    float* __restrict__ ts, float* __restrict__ tc)
{
    int j = blockIdx.x * 256 + threadIdx.x;
    if (j < NSHAPE) {
        const float* w = Ws + (size_t)j * HALF;
        float s = 0.f;
        #pragma unroll
        for (int k = 0; k < HALF; ++k) s = fmaf(w[k], w[k], s);
        ts[j] = s;
    } else if (j - NSHAPE < NCOLOR) {
        int jc = j - NSHAPE;
        const float* w = Wc + (size_t)jc * HALF;
        float s = 0.f;
        #pragma unroll
        for (int k = 0; k < HALF; ++k) s = fmaf(w[k], w[k], s);
        tc[jc] = s;
    }
}

__global__ __launch_bounds__(256) void rows_sq_k(
    const float* __restrict__ input,
    float* __restrict__ Ss, float* __restrict__ Sc)
{
    int r = blockIdx.x * 256 + threadIdx.x;
    int b = r >> 10, hw = r & 1023;
    const float* __restrict__ xin = input + ((size_t)b << 18) + hw;
    float s = 0.f;
    #pragma unroll
    for (int k = 0; k < HALF; ++k) {
        float v = xin[(size_t)k << 10];
        s = fmaf(v, v, s);
    }
    Ss[r] = s;
    float s2 = 0.f;
    #pragma unroll
    for (int k = 0; k < HALF; ++k) {
        float v = xin[(size_t)(k + HALF) << 10];
        s2 = fmaf(v, v, s2);
    }
    Sc[r] = s2;
}

__global__ __launch_bounds__(256, 3) void gemm_argmin_k(
    const float* __restrict__ input,
    const float* __restrict__ Ws, const float* __restrict__ Wc,
    const float* __restrict__ ts, const float* __restrict__ tc,
    const float* __restrict__ Ss, const float* __restrict__ Sc,
    unsigned long long* __restrict__ bs, unsigned long long* __restrict__ bc)
{
    __shared__ __align__(16) char smem[49152];
    float (*xs)[128] = reinterpret_cast<float(*)[128]>(smem);          // [32k][128r]
    float (*wt)[256] = reinterpret_cast<float(*)[256]>(smem + 16384);  // [32k][256c]

    int d = blockIdx.x;
    int o = (d & 7) * (NBLKS / 8) + (d >> 3);   // bijective XCD swizzle

    int rowblk, c0, featoff;
    const float* W; const float* tv; const float* Sarr;
    unsigned long long* bestArr;
    if (o < NSB) {
        rowblk = o >> 5; c0 = (o & 31) << 8; featoff = 0;
        W = Ws; tv = ts; Sarr = Ss; bestArr = bs;
    } else {
        int o2 = o - NSB;
        rowblk = o2 >> 1; c0 = (o2 & 1) << 8; featoff = HALF;
        W = Wc; tv = tc; Sarr = Sc; bestArr = bc;
    }

    int tid = threadIdx.x;
    int tr = tid & 15, tcg = tid >> 4;
    int r0 = rowblk << 7;
    int b = r0 >> 10, hw0 = r0 & 1023;
    const float* __restrict__ xbase =
        input + ((size_t)b << 18) + ((size_t)featoff << 10) + hw0;
    const float* __restrict__ wbase = W + ((size_t)c0 << 7);

    float acc[8][16];
    #pragma unroll
    for (int i = 0; i < 8; ++i)
        #pragma unroll
        for (int j = 0; j < 16; ++j) acc[i][j] = 0.f;

    int kl = tid >> 3, rq8 = tid & 7;     // X staging: k-row, row-quad
    int wkq = tid & 7, wcs = tid >> 3;    // W staging: k-quad, c-stripe

    for (int ks = 0; ks < 4; ++ks) {
        if (ks) __syncthreads();
        // ---- stage X: xs[k][slot(rq)^4], conflict-free (bankquad = rq8^kl) --
        {
            const float* __restrict__ gp = xbase + ((size_t)((ks << 5) + kl) << 10);
            #pragma unroll
            for (int p = 0; p < 4; ++p) {
                int rq = rq8 + (p << 3);
                float4 v = *(const float4*)(gp + (rq << 2));
                *(float4*)&xs[kl][(rq ^ kl) << 2] = v;
            }
            // ---- stage W transposed: wt[k][quad-swizzled c] (4-way residual)
            #pragma unroll
            for (int q = 0; q < 8; ++q) {
                int c = (q << 5) + wcs;
                float4 v = *(const float4*)(wbase + ((size_t)c << 7)
                                            + (ks << 5) + (wkq << 2));
                int cquad = c >> 2, cm = c & 3;
                int k0 = wkq << 2;
                wt[k0 + 0][((cquad ^ (k0 + 0)) << 2) + cm] = v.x;
                wt[k0 + 1][((cquad ^ (k0 + 1)) << 2) + cm] = v.y;
                wt[k0 + 2][((cquad ^ (k0 + 2)) << 2) + cm] = v.z;
                wt[k0 + 3][((cquad ^ (k0 + 3)) << 2) + cm] = v.w;
            }
        }
        __syncthreads();
        // ---- compute 32 k: serial ascending-k FMA chains per acc[i][j] ----
        #pragma unroll 4
        for (int k = 0; k < 32; ++k) {
            float4 x0 = *(const float4*)&xs[k][(tr ^ k) << 2];
            float4 x1 = *(const float4*)&xs[k][((16 | tr) ^ k) << 2];
            float4 w0 = *(const float4*)&wt[k][((tcg      ) ^ k) << 2];
            float4 w1 = *(const float4*)&wt[k][((tcg + 16) ^ k) << 2];
            float4 w2 = *(const float4*)&wt[k][((tcg + 32) ^ k) << 2];
            float4 w3 = *(const float4*)&wt[k][((tcg + 48) ^ k) << 2];
            float xv[8] = {x0.x, x0.y, x0.z, x0.w, x1.x, x1.y, x1.z, x1.w};
            float wv[16] = {w0.x, w0.y, w0.z, w0.w, w1.x, w1.y, w1.z, w1.w,
                            w2.x, w2.y, w2.z, w2.w, w3.x, w3.y, w3.z, w3.w};
            #pragma unroll
            for (int i = 0; i < 8; ++i)
                #pragma unroll
                for (int j = 0; j < 16; ++j)
                    acc[i][j] = fmaf(xv[i], wv[j], acc[i][j]);
        }
    }

    // ---- epilogue: D = fmaf(-2, acc, S + t); packed argmin ----
    float Sr[8];
    #pragma unroll
    for (int i = 0; i < 8; ++i) {
        int rl = ((i & 4) << 4) + (tr << 2) + (i & 3);
        Sr[i] = Sarr[r0 + rl];
    }
    unsigned long long bestp[8];
    #pragma unroll
    for (int i = 0; i < 8; ++i) bestp[i] = ~0ull;
    #pragma unroll
    for (int j = 0; j < 16; ++j) {
        int cl = ((j >> 2) << 6) + (tcg << 2) + (j & 3);
        int cgj = c0 + cl;
        float tj = tv[cgj];
        #pragma unroll
        for (int i = 0; i < 8; ++i) {
            float Sp = Sr[i] + tj;
            float D = fmaf(-2.0f, acc[i][j], Sp);   // == Sp - 2*a bitwise
            unsigned long long p =
                ((unsigned long long)mono_f32(D) << 32) | (unsigned)cgj;
            if (p < bestp[i]) bestp[i] = p;
        }
    }

    __syncthreads();   // done with xs/wt; reuse as reduction grid [128][17] u64
    unsigned long long* red = reinterpret_cast<unsigned long long*>(smem);
    #pragma unroll
    for (int i = 0; i < 8; ++i) {
        int rl = ((i & 4) << 4) + (tr << 2) + (i & 3);
        red[rl * 17 + tcg] = bestp[i];
    }
    __syncthreads();
    if (tid < 128) {
        unsigned long long m = red[tid * 17];
        #pragma unroll
        for (int q = 1; q < 16; ++q) {
            unsigned long long v = red[tid * 17 + q];
            if (v < m) m = v;
        }
        atomicMin(&bestArr[r0 + tid], m);
    }
}

__global__ __launch_bounds__(256) void finalize_k(
    const float* __restrict__ input,
    const float* __restrict__ Ws, const float* __restrict__ Wc,
    const unsigned long long* __restrict__ bs,
    const unsigned long long* __restrict__ bc,
    unsigned* __restrict__ cnt_s, unsigned* __restrict__ cnt_c,
    double* __restrict__ loss_sum, float* __restrict__ out)
{
    int tid = threadIdx.x;
    int r = blockIdx.x * 256 + tid;

    int bi = (int)(bs[r] & 0xFFFFFFFFu);
    int ci = (int)(bc[r] & 0xFFFFFFFFu);
    atomicAdd(&cnt_s[bi], 1u);
    atomicAdd(&cnt_c[ci], 1u);

    int b = r >> 10; int hw = r & 1023;
    const float* __restrict__ xin = input + ((size_t)b << 18) + hw;
    float* __restrict__ op = out + ((size_t)b << 18) + hw;
    const float* __restrict__ qs = Ws + ((size_t)bi << 7);
    const float* __restrict__ qc = Wc + ((size_t)ci << 7);

    double ls = 0.0;
    #pragma unroll 8
    for (int c = 0; c < HALF; ++c) {
        float f = xin[(size_t)c << 10];
        float dd = qs[c] - f;                  // fp32(q - f)
        op[(size_t)c << 10] = f + dd;          // fp32(f + fp32(q - f))
        ls += (double)dd * (double)dd;
    }
    #pragma unroll 8
    for (int c = 0; c < HALF; ++c) {
        float f = xin[(size_t)(c + HALF) << 10];
        float dd = qc[c] - f;
        op[(size_t)(c + HALF) << 10] = f + dd;
        ls += (double)dd * (double)dd;
    }

    __shared__ double red[256];
    red[tid] = ls;
    __syncthreads();
    for (int s = 128; s > 0; s >>= 1) {
        if (tid < s) red[tid] += red[tid + s];
        __syncthreads();
    }
    if (tid == 0) atomicAdd(loss_sum, red[0]);
}

__global__ __launch_bounds__(256) void scalars_k(
    const unsigned* __restrict__ cnt_s, const unsigned* __restrict__ cnt_c,
    const double* __restrict__ loss_sum, float* __restrict__ out3)
{
    int tid = threadIdx.x;
    double es = 0.0, ec = 0.0;
    for (int j = tid; j < NSHAPE; j += 256) {
        float p = (float)cnt_s[j] / 32768.0f;
        es += (double)(p * logf(p + 1e-10f));
    }
    for (int j = tid; j < NCOLOR; j += 256) {
        float p = (float)cnt_c[j] / 32768.0f;
        ec += (double)(p * logf(p + 1e-10f));
    }
    __shared__ double r1[256], r2[256];
    r1[tid] = es; r2[tid] = ec;
    __syncthreads();
    for (int s = 128; s > 0; s >>= 1) {
        if (tid < s) { r1[tid] += r1[tid + s]; r2[tid] += r2[tid + s]; }
        __syncthreads();
    }
    if (tid == 0) {
        out3[0] = (float)(1.25 * loss_sum[0] / 8388608.0);  // q + 0.25*e latent
        out3[1] = expf(-(float)r1[0]);
        out3[2] = expf(-(float)r2[0]);
    }
}

extern "C" void kernel_launch(void* const* d_in, const int* in_sizes, int n_in,
                              void* d_out, int out_size, void* d_ws, size_t ws_size,
                              hipStream_t stream)
{
    const float* input = (const float*)d_in[0];
    const float* Ws    = (const float*)d_in[1];
    const float* Wc    = (const float*)d_in[2];
    float* out = (float*)d_out;
    char* ws = (char*)d_ws;

    float*    ts       = (float*)(ws + OFF_TS);
    float*    tcx      = (float*)(ws + OFF_TC);
    unsigned* cnt_s    = (unsigned*)(ws + OFF_CNT_S);
    unsigned* cnt_c    = (unsigned*)(ws + OFF_CNT_C);
    double*   loss_sum = (double*)(ws + OFF_LOSS);
    float*    Ss       = (float*)(ws + OFF_SS);
    float*    Sc       = (float*)(ws + OFF_SC);
    unsigned long long* bs = (unsigned long long*)(ws + OFF_BS);
    unsigned long long* bc = (unsigned long long*)(ws + OFF_BC);

    // counts + loss: zero.  best arrays: 0xFF (== u64 max sentinel).
    hipMemsetAsync(ws + OFF_CNT_S, 0, (OFF_LOSS + 8u) - OFF_CNT_S, stream);
    hipMemsetAsync(ws + OFF_BS, 0xFF, OFF_END - OFF_BS, stream);

    codes_sq_k<<<(NSHAPE + NCOLOR + 255) / 256, 256, 0, stream>>>(Ws, Wc, ts, tcx);
    rows_sq_k<<<NROWS / 256, 256, 0, stream>>>(input, Ss, Sc);

    gemm_argmin_k<<<NBLKS, 256, 0, stream>>>(
        input, Ws, Wc, ts, tcx, Ss, Sc, bs, bc);

    finalize_k<<<NROWS / 256, 256, 0, stream>>>(
        input, Ws, Wc, bs, bc, cnt_s, cnt_c, loss_sum, out);

    scalars_k<<<1, 256, 0, stream>>>(cnt_s, cnt_c, loss_sum, out + 8388608);
}

// Round 6
// 885.748 us; speedup vs baseline: 4.5253x; 4.5253x over previous
//
#include <hip/hip_runtime.h>
#include <hip/hip_bf16.h>
#include <math.h>

// FactorizedVectorQuantizer MI355X (gfx950) — R6: pre-transposed W +
// global_load_lds staging for BOTH operands, R4's proven 8x8 compute core.
//
// rows 32768, feats 256 = 128 shape + 128 color; codebooks 8192x128, 512x128.
// Bit-exact numpy pipeline: D = fmaf(-2, dot, S + t); dot and S are single
// serial ascending-k fp32 FMA chains; argmin = lowest index on ties via
// packed u64 atomicMin key (mono(D)<<32 | code).
//
// wtr_k pre-transposes both codebooks into Wt[128][8704] (stored in d_out,
// which finalize_k fully overwrites afterwards). gemm staging is then pure
// global_load_lds dwordx4 into linear LDS (no ds_writes, no conflicts).

#define NROWS   32768
#define NSHAPE  8192
#define NCOLOR  512
#define HALF    128
#define NCODES  8704                // 8192 + 512 transposed columns

#define NSB     16384               // 256 rowblks x 64 colblks (shape)
#define NCB     1024                // 256 rowblks x 4 colblks (color)
#define NBLKS   (NSB + NCB)         // 17408, divisible by 8

// workspace byte offsets (Wt lives in d_out scratch, not here)
#define OFF_TS    0u                // f32[8192]
#define OFF_TC    32768u            // f32[512]
#define OFF_CNT_S 34816u            // u32[8192]
#define OFF_CNT_C 67584u            // u32[512]
#define OFF_LOSS  69632u            // double
#define OFF_SS    69648u            // f32[32768]
#define OFF_SC    200720u           // f32[32768]
#define OFF_BS    331792u           // u64[32768] packed best (shape)
#define OFF_BC    593936u           // u64[32768] packed best (color)
#define OFF_END   856080u

typedef __attribute__((address_space(3))) unsigned int  lds_u32;
typedef __attribute__((address_space(1))) const unsigned int gbl_u32;

__device__ __forceinline__ unsigned mono_f32(float d) {
    unsigned u = __float_as_uint(d);
    return (u & 0x80000000u) ? ~u : (u | 0x80000000u);
}

__global__ __launch_bounds__(256) void codes_sq_k(
    const float* __restrict__ Ws, const float* __restrict__ Wc,
    float* __restrict__ ts, float* __restrict__ tc)
{
    int j = blockIdx.x * 256 + threadIdx.x;
    if (j < NSHAPE) {
        const float* w = Ws + (size_t)j * HALF;
        float s = 0.f;
        #pragma unroll
        for (int k = 0; k < HALF; ++k) s = fmaf(w[k], w[k], s);
        ts[j] = s;
    } else if (j - NSHAPE < NCOLOR) {
        int jc = j - NSHAPE;
        const float* w = Wc + (size_t)jc * HALF;
        float s = 0.f;
        #pragma unroll
        for (int k = 0; k < HALF; ++k) s = fmaf(w[k], w[k], s);
        tc[jc] = s;
    }
}

__global__ __launch_bounds__(256) void rows_sq_k(
    const float* __restrict__ input,
    float* __restrict__ Ss, float* __restrict__ Sc)
{
    int r = blockIdx.x * 256 + threadIdx.x;
    int b = r >> 10, hw = r & 1023;
    const float* __restrict__ xin = input + ((size_t)b << 18) + hw;
    float s = 0.f;
    #pragma unroll
    for (int k = 0; k < HALF; ++k) {
        float v = xin[(size_t)k << 10];
        s = fmaf(v, v, s);
    }
    Ss[r] = s;
    float s2 = 0.f;
    #pragma unroll
    for (int k = 0; k < HALF; ++k) {
        float v = xin[(size_t)(k + HALF) << 10];
        s2 = fmaf(v, v, s2);
    }
    Sc[r] = s2;
}

// transpose both codebooks into Wt[128][8704] (verbatim bit copies)
__global__ __launch_bounds__(256) void wtr_k(
    const float* __restrict__ Ws, const float* __restrict__ Wc,
    float* __restrict__ Wt)
{
    __shared__ float tile[32][65];
    int c0 = blockIdx.x << 6;           // 136 blocks of 64 codes
    int k0 = blockIdx.y << 5;           // 4 blocks of 32 k
    int tid = threadIdx.x;
    const float* src; int cl0;
    if (c0 < NSHAPE) { src = Ws; cl0 = c0; } else { src = Wc; cl0 = c0 - NSHAPE; }
    int kk = tid & 31, cc = tid >> 5;   // coalesced along k
    #pragma unroll
    for (int p = 0; p < 8; ++p) {
        int c = cc + (p << 3);
        tile[kk][c] = src[(size_t)(cl0 + c) * HALF + k0 + kk];
    }
    __syncthreads();
    int c2 = tid & 63, kr0 = (tid >> 6) << 3;
    #pragma unroll
    for (int p = 0; p < 8; ++p) {
        int kr = kr0 + p;
        Wt[(size_t)(k0 + kr) * NCODES + c0 + c2] = tile[kr][c2];
    }
}

__global__ __launch_bounds__(256, 4) void gemm_argmin_k(
    const float* __restrict__ input, const float* __restrict__ wtg,
    const float* __restrict__ ts, const float* __restrict__ tc,
    const float* __restrict__ Ss, const float* __restrict__ Sc,
    unsigned long long* __restrict__ bs, unsigned long long* __restrict__ bc)
{
    __shared__ __align__(16) char smem[32768];
    float (*xs)[128] = reinterpret_cast<float(*)[128]>(smem);           // [32][128]
    float (*wt)[128] = reinterpret_cast<float(*)[128]>(smem + 16384);   // [32][128]

    int d = blockIdx.x;
    int o = (d & 7) * (NBLKS / 8) + (d >> 3);   // bijective XCD swizzle

    int rowblk, c0w, cgb, featoff;
    const float* tv; const float* Sarr; unsigned long long* bestArr;
    if (o < NSB) {
        rowblk = o >> 6; int cb = o & 63;
        c0w = cb << 7;                 // Wt column base
        cgb = cb << 7;                 // reported code base (shape book)
        featoff = 0; tv = ts; Sarr = Ss; bestArr = bs;
    } else {
        int o2 = o - NSB;
        rowblk = o2 >> 2; int cb = o2 & 3;
        c0w = NSHAPE + (cb << 7);
        cgb = cb << 7;                 // color book local index
        featoff = HALF; tv = tc; Sarr = Sc; bestArr = bc;
    }

    int tid = threadIdx.x;
    int lane = tid & 63;
    int wv = __builtin_amdgcn_readfirstlane(tid >> 6);   // wave id 0..3
    int r0 = rowblk << 7;
    int b = r0 >> 10, hw0 = r0 & 1023;

    // per-lane DMA source bases (lane covers 16B chunk; lane>>5 = row parity)
    const float* __restrict__ xg =
        input + ((size_t)b << 18) + ((size_t)featoff << 10) + hw0
              + ((size_t)(lane >> 5) << 10) + ((lane & 31) << 2);
    const float* __restrict__ wg =
        wtg + (size_t)(lane >> 5) * NCODES + c0w + ((lane & 31) << 2);

    int tr = tid & 15, tcg = tid >> 4;

    float acc[8][8] = {{0.f}};

    for (int ks = 0; ks < 4; ++ks) {
        if (ks) __syncthreads();   // all waves done reading previous tiles
        // ---- stage X and W tiles via async global->LDS DMA (linear dest) --
        #pragma unroll
        for (int i = 0; i < 4; ++i) {
            int kx = (wv << 3) + (i << 1);               // wave-uniform
            const float* gx = xg + ((size_t)((ks << 5) + kx) << 10);
            __builtin_amdgcn_global_load_lds(
                (gbl_u32*)gx, (lds_u32*)&xs[kx][0], 16, 0, 0);
            const float* gw = wg + (size_t)((ks << 5) + kx) * NCODES;
            __builtin_amdgcn_global_load_lds(
                (gbl_u32*)gw, (lds_u32*)&wt[kx][0], 16, 0, 0);
        }
        __syncthreads();   // compiler drains vmcnt(0) -> tiles visible
        // ---- compute 32 k: serial ascending-k FMA chains per acc[i][j] ----
        #pragma unroll 8
        for (int k = 0; k < 32; ++k) {
            float4 x0 = *(const float4*)&xs[k][tr << 2];
            float4 x1 = *(const float4*)&xs[k][64 + (tr << 2)];
            float4 w0 = *(const float4*)&wt[k][tcg << 2];
            float4 w1 = *(const float4*)&wt[k][64 + (tcg << 2)];
            float xv[8] = {x0.x, x0.y, x0.z, x0.w, x1.x, x1.y, x1.z, x1.w};
            float wv8[8] = {w0.x, w0.y, w0.z, w0.w, w1.x, w1.y, w1.z, w1.w};
            #pragma unroll
            for (int i = 0; i < 8; ++i)
                #pragma unroll
                for (int j = 0; j < 8; ++j)
                    acc[i][j] = fmaf(xv[i], wv8[j], acc[i][j]);
        }
    }

    // ---- epilogue: D = fmaf(-2, acc, S + t); packed argmin ----
    float Sr[8];
    #pragma unroll
    for (int i = 0; i < 8; ++i) {
        int rl = ((i & 4) << 4) + (tr << 2) + (i & 3);
        Sr[i] = Sarr[r0 + rl];
    }
    unsigned long long bestp[8];
    #pragma unroll
    for (int i = 0; i < 8; ++i) bestp[i] = ~0ull;
    #pragma unroll
    for (int j = 0; j < 8; ++j) {
        int cl = ((j & 4) << 4) + (tcg << 2) + (j & 3);
        int cgj = cgb + cl;
        float tj = tv[cgj];
        #pragma unroll
        for (int i = 0; i < 8; ++i) {
            float Sp = Sr[i] + tj;
            float D = fmaf(-2.0f, acc[i][j], Sp);   // == Sp - 2*a bitwise
            unsigned long long p =
                ((unsigned long long)mono_f32(D) << 32) | (unsigned)cgj;
            if (p < bestp[i]) bestp[i] = p;
        }
    }

    __syncthreads();   // tiles dead; reuse smem as reduction grid [128][17] u64
    unsigned long long* red = reinterpret_cast<unsigned long long*>(smem);
    #pragma unroll
    for (int i = 0; i < 8; ++i) {
        int rl = ((i & 4) << 4) + (tr << 2) + (i & 3);
        red[rl * 17 + tcg] = bestp[i];
    }
    __syncthreads();
    if (tid < 128) {
        unsigned long long m = red[tid * 17];
        #pragma unroll
        for (int q = 1; q < 16; ++q) {
            unsigned long long v = red[tid * 17 + q];
            if (v < m) m = v;
        }
        atomicMin(&bestArr[r0 + tid], m);
    }
}

__global__ __launch_bounds__(256) void finalize_k(
    const float* __restrict__ input,
    const float* __restrict__ Ws, const float* __restrict__ Wc,
    const unsigned long long* __restrict__ bs,
    const unsigned long long* __restrict__ bc,
    unsigned* __restrict__ cnt_s, unsigned* __restrict__ cnt_c,
    double* __restrict__ loss_sum, float* __restrict__ out)
{
    int tid = threadIdx.x;
    int r = blockIdx.x * 256 + tid;

    int bi = (int)(bs[r] & 0xFFFFFFFFu);
    int ci = (int)(bc[r] & 0xFFFFFFFFu);
    atomicAdd(&cnt_s[bi], 1u);
    atomicAdd(&cnt_c[ci], 1u);

    int b = r >> 10; int hw = r & 1023;
    const float* __restrict__ xin = input + ((size_t)b << 18) + hw;
    float* __restrict__ op = out + ((size_t)b << 18) + hw;
    const float* __restrict__ qs = Ws + ((size_t)bi << 7);
    const float* __restrict__ qc = Wc + ((size_t)ci << 7);

    double ls = 0.0;
    #pragma unroll 8
    for (int c = 0; c < HALF; ++c) {
        float f = xin[(size_t)c << 10];
        float dd = qs[c] - f;                  // fp32(q - f)
        op[(size_t)c << 10] = f + dd;          // fp32(f + fp32(q - f))
        ls += (double)dd * (double)dd;
    }
    #pragma unroll 8
    for (int c = 0; c < HALF; ++c) {
        float f = xin[(size_t)(c + HALF) << 10];
        float dd = qc[c] - f;
        op[(size_t)(c + HALF) << 10] = f + dd;
        ls += (double)dd * (double)dd;
    }

    __shared__ double red[256];
    red[tid] = ls;
    __syncthreads();
    for (int s = 128; s > 0; s >>= 1) {
        if (tid < s) red[tid] += red[tid + s];
        __syncthreads();
    }
    if (tid == 0) atomicAdd(loss_sum, red[0]);
}

__global__ __launch_bounds__(256) void scalars_k(
    const unsigned* __restrict__ cnt_s, const unsigned* __restrict__ cnt_c,
    const double* __restrict__ loss_sum, float* __restrict__ out3)
{
    int tid = threadIdx.x;
    double es = 0.0, ec = 0.0;
    for (int j = tid; j < NSHAPE; j += 256) {
        float p = (float)cnt_s[j] / 32768.0f;
        es += (double)(p * logf(p + 1e-10f));
    }
    for (int j = tid; j < NCOLOR; j += 256) {
        float p = (float)cnt_c[j] / 32768.0f;
        ec += (double)(p * logf(p + 1e-10f));
    }
    __shared__ double r1[256], r2[256];
    r1[tid] = es; r2[tid] = ec;
    __syncthreads();
    for (int s = 128; s > 0; s >>= 1) {
        if (tid < s) { r1[tid] += r1[tid + s]; r2[tid] += r2[tid + s]; }
        __syncthreads();
    }
    if (tid == 0) {
        out3[0] = (float)(1.25 * loss_sum[0] / 8388608.0);  // q + 0.25*e latent
        out3[1] = expf(-(float)r1[0]);
        out3[2] = expf(-(float)r2[0]);
    }
}

extern "C" void kernel_launch(void* const* d_in, const int* in_sizes, int n_in,
                              void* d_out, int out_size, void* d_ws, size_t ws_size,
                              hipStream_t stream)
{
    const float* input = (const float*)d_in[0];
    const float* Ws    = (const float*)d_in[1];
    const float* Wc    = (const float*)d_in[2];
    float* out = (float*)d_out;
    char* ws = (char*)d_ws;

    float*    ts       = (float*)(ws + OFF_TS);
    float*    tcx      = (float*)(ws + OFF_TC);
    unsigned* cnt_s    = (unsigned*)(ws + OFF_CNT_S);
    unsigned* cnt_c    = (unsigned*)(ws + OFF_CNT_C);
    double*   loss_sum = (double*)(ws + OFF_LOSS);
    float*    Ss       = (float*)(ws + OFF_SS);
    float*    Sc       = (float*)(ws + OFF_SC);
    unsigned long long* bs = (unsigned long long*)(ws + OFF_BS);
    unsigned long long* bc = (unsigned long long*)(ws + OFF_BC);

    // Wt[128][8704] lives in d_out (finalize_k fully overwrites d_out later)
    float* Wt = out;

    // counts + loss: zero.  best arrays: 0xFF (== u64 max sentinel).
    hipMemsetAsync(ws + OFF_CNT_S, 0, (OFF_LOSS + 8u) - OFF_CNT_S, stream);
    hipMemsetAsync(ws + OFF_BS, 0xFF, OFF_END - OFF_BS, stream);

    codes_sq_k<<<(NSHAPE + NCOLOR + 255) / 256, 256, 0, stream>>>(Ws, Wc, ts, tcx);
    rows_sq_k<<<NROWS / 256, 256, 0, stream>>>(input, Ss, Sc);
    wtr_k<<<dim3(NCODES / 64, 4), 256, 0, stream>>>(Ws, Wc, Wt);

    gemm_argmin_k<<<NBLKS, 256, 0, stream>>>(
        input, Wt, ts, tcx, Ss, Sc, bs, bc);

    finalize_k<<<NROWS / 256, 256, 0, stream>>>(
        input, Ws, Wc, bs, bc, cnt_s, cnt_c, loss_sum, out);

    scalars_k<<<1, 256, 0, stream>>>(cnt_s, cnt_c, loss_sum, out + 8388608);
}